// Round 4
// baseline (267.225 us; speedup 1.0000x reference)
//
#include <hip/hip_runtime.h>

// ---------------------------------------------------------------------------
// MultiHeadAttention: x[4,2048,1024] -> qkv -> causal attn (H=16, Dh=64) -> proj
//   k_cvt:        x fp32 -> bf16 [8192][1024]
//   k_transpose:  w fp32 [K][N] -> bf16 [N][K]
//   k_gemm256:    qkv = x @ w_qkv + b (256x256 tile, 8-wave, counted-vmcnt
//                 deep pipeline, 32x32x16 MFMA) -> Q (pre-scaled), K, V^T
//   k_attn:       flash attn, 32x32 MFMA, swapped QK^T, in-register P
//   k_gemm<1>:    out = a @ w_proj + b (fp32 out, m97 structure)
// ---------------------------------------------------------------------------

typedef __bf16 bf16x8 __attribute__((ext_vector_type(8)));
typedef float f32x4 __attribute__((ext_vector_type(4)));
typedef float f32x8 __attribute__((ext_vector_type(8)));
typedef float f32x16 __attribute__((ext_vector_type(16)));
typedef unsigned int u32;
typedef u32 u32x4 __attribute__((ext_vector_type(4)));
typedef unsigned short u16;

#define QSCALE 0.18033688011112042f  // 0.125 * log2(e), folded into Q

__device__ __forceinline__ u16 f2bf(float f) {
  unsigned u = __builtin_bit_cast(unsigned, f);
  return (u16)((u + 0x7FFFu + ((u >> 16) & 1u)) >> 16);  // RNE
}

__device__ __forceinline__ u32 cvt_pk_bf16(float lo, float hi) {
  u32 r;
  asm("v_cvt_pk_bf16_f32 %0, %1, %2" : "=v"(r) : "v"(lo), "v"(hi));
  return r;
}

__device__ __forceinline__ void gload16(const void* g, void* l) {
  __builtin_amdgcn_global_load_lds(
      (const __attribute__((address_space(1))) unsigned*)g,
      (__attribute__((address_space(3))) unsigned*)l, 16, 0, 0);
}

// ---------------------------------------------------------------------------
__global__ __launch_bounds__(256) void k_cvt(const float4* __restrict__ in,
                                             ushort4* __restrict__ out, int n4) {
  int i = blockIdx.x * 256 + threadIdx.x;
  if (i < n4) {
    float4 v = in[i];
    out[i] = make_ushort4(f2bf(v.x), f2bf(v.y), f2bf(v.z), f2bf(v.w));
  }
}

__global__ __launch_bounds__(256) void k_transpose(const float* __restrict__ in,
                                                   u16* __restrict__ out, int R, int C) {
  __shared__ u16 tile[32][33];
  int c0 = blockIdx.x * 32, r0 = blockIdx.y * 32;
  int tx = threadIdx.x & 31, ty = threadIdx.x >> 5;
  for (int i = 0; i < 32; i += 8)
    tile[ty + i][tx] = f2bf(in[(size_t)(r0 + ty + i) * C + c0 + tx]);
  __syncthreads();
  for (int i = 0; i < 32; i += 8)
    out[(size_t)(c0 + ty + i) * R + r0 + tx] = tile[tx][ty + i];
}

// ---------------------------------------------------------------------------
// 256x256 deep-pipelined QKV GEMM. 512 thr = 8 waves (2M x 4N), per-wave
// 128x64 out via 32x32x16 MFMA (acc[4][2] f32x16). BK=64; LDS = 2 tile-bufs
// x {A,B} x 2 halves x (128 rows x 128B) = 128 KB, granule-^(row&7) swizzled.
// Per phase: stage 1 half-tile of T+1 (2 gload16/thr), vmcnt(6) [tail 4/2/0],
// barrier, class-scheduled {ds_read + 8 MFMA}, lgkmcnt(0), barrier.
// Half availability (pending = last 3 staged halves): A0,B0@P0, A1@P1, B1@P2.
// Class schedules (all reads <= P3; cross-phase uses are register-only):
//  cls0 (wm0,hb0): P0 LDA0,LDB0,Q00 | P1 LDB1,Q01 | P2 LDA1,Q11 | P3 Q10
//  cls2 (wm1,hb0): P0 Q10(prev)     | P1 LDA0,LDB0,Q00 | P2 LDB1,Q01 | P3 LDA1,Q11
//  cls1/3 (hb1):   P0 Q11(p) | P1 Q10(p) | P2 LDA0,LDB0,Q00 | P3 LDA1,LDB1,Q01
// Drain: cls2 Q10; cls1/3 Q11,Q10.
__global__ __launch_bounds__(512, 2) void k_gemm256(
    const u16* __restrict__ A, const u16* __restrict__ Bt,
    const float* __restrict__ bias,
    u16* __restrict__ qb, u16* __restrict__ kb, u16* __restrict__ vb, int K) {
  __shared__ u16 lds[2][2][2][8192];
  const int b0 = blockIdx.x;
  const int bsw = (b0 & 7) * 48 + (b0 >> 3);  // XCD swizzle (384 % 8 == 0)
  const int tm = bsw / 12, tn = bsw % 12;
  const int t = threadIdx.x, w = t >> 6, lane = t & 63;
  const int wm = w >> 2, wn = w & 3, hb = wn >> 1;
  const int cls = wm * 2 + hb;
  const int l31 = lane & 31, h8 = lane >> 5;
  const int sg8 = ((lane & 7) ^ (lane >> 3)) << 3;  // staging src swizzle (u16)
  const int NT = K >> 6;
  const u16* Ag = A + (size_t)tm * 256 * K;
  const u16* Bg = Bt + (size_t)tn * 256 * K;

  f32x16 acc[4][2] = {};
  bf16x8 aR[4][4], bR[2][4];

#define STAGE_HALF(P, Tn)                                                     \
  {                                                                           \
    const u16* gb = ((P)&1) ? Bg : Ag;                                        \
    _Pragma("unroll") for (int r = 0; r < 2; r++) {                           \
      int row = r * 64 + w * 8 + (lane >> 3);                                 \
      gload16(gb + (size_t)(((P) >> 1) * 128 + row) * K + (Tn)*64 + sg8,      \
              (char*)&lds[(Tn)&1][(P)&1][(P) >> 1][0] + r * 8192 + w * 1024); \
    }                                                                         \
  }
#define LDA(mg)                                                                \
  _Pragma("unroll") for (int mf = (mg)*2; mf < (mg)*2 + 2; mf++)               \
  _Pragma("unroll") for (int ks = 0; ks < 4; ks++)                             \
    aR[mf][ks] = *(const bf16x8*)(Abase + (mf * 32 + l31) * 128 +              \
                                  (((ks * 2 + h8) ^ (l31 & 7)) << 4));
#define LDB(nf)                                                                \
  _Pragma("unroll") for (int ks = 0; ks < 4; ks++)                             \
    bR[nf][ks] = *(const bf16x8*)(Bbase + ((wn & 1) * 64 + (nf)*32 + l31) * 128 + \
                                  (((ks * 2 + h8) ^ (l31 & 7)) << 4));
#define MQ(mg, nf)                                                             \
  {                                                                            \
    __builtin_amdgcn_s_setprio(1);                                             \
    _Pragma("unroll") for (int mf = (mg)*2; mf < (mg)*2 + 2; mf++)             \
    _Pragma("unroll") for (int ks = 0; ks < 4; ks++)                           \
      acc[mf][nf] = __builtin_amdgcn_mfma_f32_32x32x16_bf16(                   \
          aR[mf][ks], bR[nf][ks], acc[mf][nf], 0, 0, 0);                       \
    __builtin_amdgcn_s_setprio(0);                                             \
  }
#define PH(P, QBODY)                                                           \
  {                                                                            \
    if (T + 1 < NT) {                                                          \
      STAGE_HALF(P, T + 1);                                                    \
      asm volatile("s_waitcnt vmcnt(6)" ::: "memory");                         \
    } else {                                                                   \
      if ((P) == 0) asm volatile("s_waitcnt vmcnt(4)" ::: "memory");           \
      else if ((P) == 1) asm volatile("s_waitcnt vmcnt(2)" ::: "memory");      \
      else if ((P) == 2) asm volatile("s_waitcnt vmcnt(0)" ::: "memory");      \
    }                                                                          \
    __builtin_amdgcn_sched_barrier(0);                                         \
    __builtin_amdgcn_s_barrier();                                              \
    __builtin_amdgcn_sched_barrier(0);                                         \
    const char* Abase = (const char*)&lds[T & 1][0][wm][0];                    \
    const char* Bbase = (const char*)&lds[T & 1][1][hb][0];                    \
    (void)Abase; (void)Bbase;                                                  \
    QBODY                                                                      \
    asm volatile("s_waitcnt lgkmcnt(0)" ::: "memory");                         \
    __builtin_amdgcn_sched_barrier(0);                                         \
    __builtin_amdgcn_s_barrier();                                              \
    __builtin_amdgcn_sched_barrier(0);                                         \
  }

  // prologue: stage all 4 halves of tile 0
  STAGE_HALF(0, 0);
  STAGE_HALF(1, 0);
  STAGE_HALF(2, 0);
  STAGE_HALF(3, 0);

  for (int T = 0; T < NT; ++T) {
    PH(0, {
      if (cls == 0)      { LDA(0); LDB(0); MQ(0, 0); }
      else if (cls == 2) { if (T) MQ(1, 0); }
      else               { if (T) MQ(1, 1); }
    })
    PH(1, {
      if (cls == 0)      { LDB(1); MQ(0, 1); }
      else if (cls == 2) { LDA(0); LDB(0); MQ(0, 0); }
      else               { if (T) MQ(1, 0); }
    })
    PH(2, {
      if (cls == 0)      { LDA(1); MQ(1, 1); }
      else if (cls == 2) { LDB(1); MQ(0, 1); }
      else               { LDA(0); LDB(0); MQ(0, 0); }
    })
    PH(3, {
      if (cls == 0)      { MQ(1, 0); }
      else if (cls == 2) { LDA(1); MQ(1, 1); }
      else               { LDA(1); LDB(1); MQ(0, 1); }
    })
  }
  // drain (register-only)
  if (cls == 2) { MQ(1, 0); }
  else if (cls == 1 || cls == 3) { MQ(1, 1); MQ(1, 0); }

  // epilogue: C/D 32x32 layout col = l&31, row = (r&3)+8*(r>>2)+4*h8
  const int which = tn >> 2;  // block-uniform: 0=Q 1=K 2=V (1024 % 256 == 0)
#pragma unroll
  for (int mf = 0; mf < 4; mf++) {
    const int rb = tm * 256 + wm * 128 + mf * 32 + 4 * h8;
    const int b_ = rb >> 11, sB = rb & 2047;  // tile never crosses batch
#pragma unroll
    for (int nf = 0; nf < 2; nf++) {
      const int cl = tn * 256 + wn * 64 + nf * 32 + l31;
      const float bv = bias[cl];
      const int hd = (cl >> 6) & 15, d = cl & 63;
      const size_t bh = (size_t)(b_ * 16 + hd);
      if (which == 0) {
        u16* dst = qb + (bh * 2048 + sB) * 64 + d;
#pragma unroll
        for (int r = 0; r < 16; r++)
          dst[(size_t)((r & 3) + 8 * (r >> 2)) * 64] = f2bf((acc[mf][nf][r] + bv) * QSCALE);
      } else if (which == 1) {
        u16* dst = kb + (bh * 2048 + sB) * 64 + d;
#pragma unroll
        for (int r = 0; r < 16; r++)
          dst[(size_t)((r & 3) + 8 * (r >> 2)) * 64] = f2bf(acc[mf][nf][r] + bv);
      } else {  // V^T [B,H,Dh,S]; s runs of 4 -> ushort4
        u16* dst = vb + (bh * 64 + d) * 2048 + sB;
#pragma unroll
        for (int rq = 0; rq < 4; rq++) {
          ushort4 pk = make_ushort4(
              f2bf(acc[mf][nf][rq * 4 + 0] + bv), f2bf(acc[mf][nf][rq * 4 + 1] + bv),
              f2bf(acc[mf][nf][rq * 4 + 2] + bv), f2bf(acc[mf][nf][rq * 4 + 3] + bv));
          *(ushort4*)&dst[rq * 8] = pk;
        }
      }
    }
  }
#undef STAGE_HALF
#undef LDA
#undef LDB
#undef MQ
#undef PH
}

// ---------------------------------------------------------------------------
// m97-structure GEMM (kept for the projection): C = A @ Bt^T + bias, fp32 out.
template <int MODE>
__global__ __launch_bounds__(256, 2) void k_gemm(
    const u16* __restrict__ A, const u16* __restrict__ Bt,
    const float* __restrict__ bias, float* __restrict__ outF,
    int M, int N, int K) {
  __shared__ u16 sA[128 * 32];
  __shared__ u16 sB[128 * 32];
  const int nTn = N >> 7;
  const int tm = blockIdx.x / nTn, tn = blockIdx.x % nTn;
  const int t = threadIdx.x, w = t >> 6, lane = t & 63, g = lane >> 4, c = lane & 15;
  const int wr = w >> 1, wc = w & 1;
  const int rowA0 = tm << 7, colB0 = tn << 7;
  f32x4 acc[4][4] = {};
  const int r = t >> 2, c8 = (t & 3) << 3;
  const u16* gA = A + (size_t)(rowA0 + r) * K + c8;
  const u16* gB = Bt + (size_t)(colB0 + r) * K + c8;
  char* lA = (char*)sA + w * 1024;
  char* lB = (char*)sB + w * 1024;
  for (int k0 = 0; k0 < K; k0 += 32) {
    __syncthreads();
    gload16(gA + k0, lA);
    gload16(gA + k0 + (size_t)64 * K, lA + 4096);
    gload16(gB + k0, lB);
    gload16(gB + k0 + (size_t)64 * K, lB + 4096);
    __syncthreads();
    bf16x8 af[4], bfr[4];
#pragma unroll
    for (int mi = 0; mi < 4; mi++)
      af[mi] = *(const bf16x8*)&sA[(wr * 64 + mi * 16 + c) * 32 + g * 8];
#pragma unroll
    for (int ni = 0; ni < 4; ni++)
      bfr[ni] = *(const bf16x8*)&sB[(wc * 64 + ni * 16 + c) * 32 + g * 8];
#pragma unroll
    for (int mi = 0; mi < 4; mi++)
#pragma unroll
      for (int ni = 0; ni < 4; ni++)
        acc[mi][ni] = __builtin_amdgcn_mfma_f32_16x16x32_bf16(af[mi], bfr[ni], acc[mi][ni], 0, 0, 0);
  }
#pragma unroll
  for (int mi = 0; mi < 4; mi++) {
    int row0 = rowA0 + wr * 64 + mi * 16 + g * 4;
#pragma unroll
    for (int ni = 0; ni < 4; ni++) {
      int col = colB0 + wc * 64 + ni * 16 + c;
      float bv = bias[col];
#pragma unroll
      for (int i = 0; i < 4; i++)
        outF[(size_t)(row0 + i) * N + col] = acc[mi][ni][i] + bv;
    }
  }
}

// ---------------------------------------------------------------------------
// Flash attention, 32x32x16 MFMA (unchanged from round 2).
__global__ __launch_bounds__(256, 4) void k_attn(const u16* __restrict__ qb,
                                                 const u16* __restrict__ kb,
                                                 const u16* __restrict__ vb,
                                                 u16* __restrict__ ab) {
  __shared__ u16 sK[2][64 * 64];
  __shared__ u16 sV[2][64 * 64];
  const int bid = blockIdx.x;
  const int qt = 15 - (bid >> 6), bh = bid & 63;
  const int b_ = bh >> 4, hh = bh & 15;
  const int t = threadIdx.x, w = t >> 6, lane = t & 63;
  const int l31 = lane & 31, h = lane >> 5;
  const int q0 = qt << 7, myq = q0 + w * 32;
  const u16* Kg = kb + (size_t)bh * 2048 * 64;
  const u16* Vg = vb + (size_t)bh * 64 * 2048;
  const int rr = t >> 3, p = t & 7;

  const u16* Qrow = qb + ((size_t)bh * 2048 + myq + l31) * 64;
  bf16x8 qf[4];
#pragma unroll
  for (int ks = 0; ks < 4; ks++) qf[ks] = *(const bf16x8*)&Qrow[ks * 16 + h * 8];

#define STAGE(buf, kv0_)                                                      \
  {                                                                           \
    _Pragma("unroll") for (int i = 0; i < 2; i++) {                           \
      int row = i * 32 + rr;                                                  \
      gload16(Kg + ((size_t)(kv0_) + row) * 64 + ((p ^ (row & 7)) << 3),      \
              (char*)sK[buf] + i * 4096 + w * 1024);                          \
      gload16(Vg + (size_t)row * 2048 + (kv0_) + ((p ^ (row & 7)) << 3),      \
              (char*)sV[buf] + i * 4096 + w * 1024);                          \
    }                                                                         \
  }

  f32x16 ot[2] = {};
  float mrun = -__builtin_inff(), lrun = 0.f;
  const int nt = qt * 2 + 2;

  STAGE(0, 0);
  for (int tt = 0; tt < nt; ++tt) {
    const int kv0 = tt << 6;
    __syncthreads();
    if (tt + 1 < nt) STAGE((tt + 1) & 1, kv0 + 64);
    if (kv0 > myq + 31) continue;
    const char* bK = (const char*)sK[tt & 1];
    const char* bV = (const char*)sV[tt & 1];

    f32x16 st[2] = {};
    __builtin_amdgcn_s_setprio(1);
#pragma unroll
    for (int ks = 0; ks < 4; ks++)
#pragma unroll
      for (int kvt = 0; kvt < 2; kvt++) {
        int row = kvt * 32 + l31;
        bf16x8 kf = *(const bf16x8*)(bK + row * 128 + ((ks * 32 + h * 16) ^ ((row & 7) << 4)));
        st[kvt] = __builtin_amdgcn_mfma_f32_32x32x16_bf16(kf, qf[ks], st[kvt], 0, 0, 0);
      }
    __builtin_amdgcn_s_setprio(0);

    if (kv0 + 63 > myq) {
      const int qm = myq + l31 - kv0 - 4 * h;
#pragma unroll
      for (int kvt = 0; kvt < 2; kvt++)
#pragma unroll
        for (int r = 0; r < 16; r++) {
          const int kvo = kvt * 32 + (r & 3) + 8 * (r >> 2);
          st[kvt][r] = (kvo <= qm) ? st[kvt][r] : -__builtin_inff();
        }
    }

    float mt = -__builtin_inff();
#pragma unroll
    for (int r = 0; r < 16; r++) mt = fmaxf(mt, fmaxf(st[0][r], st[1][r]));
    mt = fmaxf(mt, __shfl_xor(mt, 32, 64));
    float mnew = mrun;
    if (!__all(mt <= mrun + 8.f)) {
      mnew = fmaxf(mrun, mt);
      const float corr = __builtin_amdgcn_exp2f(mrun - mnew);
      lrun *= corr;
#pragma unroll
      for (int df = 0; df < 2; df++) ot[df] *= corr;
      mrun = mnew;
    }
#pragma unroll
    for (int kvt = 0; kvt < 2; kvt++)
#pragma unroll
      for (int r = 0; r < 16; r++) st[kvt][r] = __builtin_amdgcn_exp2f(st[kvt][r] - mnew);
    f32x16 ssum = st[0] + st[1];
    f32x8 t8 = __builtin_shufflevector(ssum, ssum, 0, 1, 2, 3, 4, 5, 6, 7) +
               __builtin_shufflevector(ssum, ssum, 8, 9, 10, 11, 12, 13, 14, 15);
    f32x4 t4 = __builtin_shufflevector(t8, t8, 0, 1, 2, 3) +
               __builtin_shufflevector(t8, t8, 4, 5, 6, 7);
    float lt = (t4[0] + t4[1]) + (t4[2] + t4[3]);
    lt += __shfl_xor(lt, 32, 64);
    lrun += lt;

    u32 pk[2][8];
#pragma unroll
    for (int kvt = 0; kvt < 2; kvt++)
#pragma unroll
      for (int j = 0; j < 8; j++)
        pk[kvt][j] = cvt_pk_bf16(st[kvt][2 * j], st[kvt][2 * j + 1]);
    __builtin_amdgcn_s_setprio(1);
#pragma unroll
    for (int s = 0; s < 4; s++) {
      const int kvf = s >> 1, jb = (s & 1) * 4;
      const u32 XloW0 = pk[kvf][jb + 0], XloW1 = pk[kvf][jb + 1];
      const u32 XhiW0 = pk[kvf][jb + 2], XhiW1 = pk[kvf][jb + 3];
      const u32 cHi0 = (u32)__shfl_xor((int)XhiW0, 32, 64);
      const u32 cHi1 = (u32)__shfl_xor((int)XhiW1, 32, 64);
      const u32 cLo0 = (u32)__shfl_xor((int)XloW0, 32, 64);
      const u32 cLo1 = (u32)__shfl_xor((int)XloW1, 32, 64);
      u32x4 pw;
      pw[0] = h ? cHi0 : XloW0;
      pw[1] = h ? cHi1 : XloW1;
      pw[2] = h ? XhiW0 : cLo0;
      pw[3] = h ? XhiW1 : cLo1;
      const bf16x8 pf = __builtin_bit_cast(bf16x8, pw);
#pragma unroll
      for (int df = 0; df < 2; df++) {
        const int row = df * 32 + l31;
        bf16x8 vf = *(const bf16x8*)(bV + row * 128 + ((s * 32 + h * 16) ^ ((row & 7) << 4)));
        ot[df] = __builtin_amdgcn_mfma_f32_32x32x16_bf16(vf, pf, ot[df], 0, 0, 0);
      }
    }
    __builtin_amdgcn_s_setprio(0);
  }

  const float inv = 1.f / lrun;
  u16* Arow = ab + ((size_t)b_ * 2048 + myq + l31) * 1024 + hh * 64;
#pragma unroll
  for (int df = 0; df < 2; df++)
#pragma unroll
    for (int qd = 0; qd < 4; qd++) {
      const int d0 = df * 32 + qd * 8 + h * 4;
      ushort4 pkv = make_ushort4(f2bf(ot[df][qd * 4 + 0] * inv), f2bf(ot[df][qd * 4 + 1] * inv),
                                 f2bf(ot[df][qd * 4 + 2] * inv), f2bf(ot[df][qd * 4 + 3] * inv));
      *(ushort4*)&Arow[d0] = pkv;
    }
#undef STAGE
}

// ---------------------------------------------------------------------------
extern "C" void kernel_launch(void* const* d_in, const int* in_sizes, int n_in,
                              void* d_out, int out_size, void* d_ws, size_t ws_size,
                              hipStream_t stream) {
  const float* x = (const float*)d_in[0];
  const float* w_qkv = (const float*)d_in[1];
  const float* b_qkv = (const float*)d_in[2];
  const float* w_proj = (const float*)d_in[3];
  const float* b_proj = (const float*)d_in[4];

  u16* xb = (u16*)d_ws;                       // 8192*1024
  u16* wqkvT = xb + (size_t)8192 * 1024;      // 3072*1024
  u16* wprojT = wqkvT + (size_t)3072 * 1024;  // 1024*1024
  u16* qb = wprojT + (size_t)1024 * 1024;     // [B,H,S,Dh] (pre-scaled)
  u16* kb = qb + (size_t)8192 * 1024;
  u16* vb = kb + (size_t)8192 * 1024;         // [B,H,Dh,S]
  u16* ab = xb;                               // reuse x_bf16

  k_cvt<<<8192, 256, 0, stream>>>((const float4*)x, (ushort4*)xb, 8192 * 1024 / 4);
  k_transpose<<<dim3(3072 / 32, 1024 / 32), 256, 0, stream>>>(w_qkv, wqkvT, 1024, 3072);
  k_transpose<<<dim3(1024 / 32, 1024 / 32), 256, 0, stream>>>(w_proj, wprojT, 1024, 1024);
  k_gemm256<<<384, 512, 0, stream>>>(xb, wqkvT, b_qkv, qb, kb, vb, 1024);
  k_attn<<<1024, 256, 0, stream>>>(qb, kb, vb, ab);
  k_gemm<1><<<(8192 / 128) * (1024 / 128), 256, 0, stream>>>(
      ab, wprojT, b_proj, (float*)d_out, 8192, 1024, 1024);
}

// Round 6
// 266.790 us; speedup vs baseline: 1.0016x; 1.0016x over previous
//
#include <hip/hip_runtime.h>

// ---------------------------------------------------------------------------
// MultiHeadAttention: x[4,2048,1024] -> qkv -> causal attn (H=16, Dh=64) -> proj
//   k_cvt:        x fp32 -> bf16 [8192][1024]
//   k_transpose:  w fp32 [K][N] -> bf16 [N][K]
//   k_gemm256:    qkv = x @ w_qkv + b. 256x256 tile, 8 waves, uniform 4-phase
//                 schedule, depth-2 tile staging, ONE vmcnt(8) per K-tile.
//   k_attn:       flash attn, 32x32 MFMA, swapped QK^T, in-register P
//   k_gemm<1>:    out = a @ w_proj + b (fp32 out, m97 structure)
// ---------------------------------------------------------------------------

typedef __bf16 bf16x8 __attribute__((ext_vector_type(8)));
typedef float f32x4 __attribute__((ext_vector_type(4)));
typedef float f32x8 __attribute__((ext_vector_type(8)));
typedef float f32x16 __attribute__((ext_vector_type(16)));
typedef unsigned int u32;
typedef u32 u32x4 __attribute__((ext_vector_type(4)));
typedef unsigned short u16;

#define QSCALE 0.18033688011112042f  // 0.125 * log2(e), folded into Q

__device__ __forceinline__ u16 f2bf(float f) {
  unsigned u = __builtin_bit_cast(unsigned, f);
  return (u16)((u + 0x7FFFu + ((u >> 16) & 1u)) >> 16);  // RNE
}

__device__ __forceinline__ u32 cvt_pk_bf16(float lo, float hi) {
  u32 r;
  asm("v_cvt_pk_bf16_f32 %0, %1, %2" : "=v"(r) : "v"(lo), "v"(hi));
  return r;
}

__device__ __forceinline__ void gload16(const void* g, void* l) {
  __builtin_amdgcn_global_load_lds(
      (const __attribute__((address_space(1))) unsigned*)g,
      (__attribute__((address_space(3))) unsigned*)l, 16, 0, 0);
}

// ---------------------------------------------------------------------------
__global__ __launch_bounds__(256) void k_cvt(const float4* __restrict__ in,
                                             ushort4* __restrict__ out, int n4) {
  int i = blockIdx.x * 256 + threadIdx.x;
  if (i < n4) {
    float4 v = in[i];
    out[i] = make_ushort4(f2bf(v.x), f2bf(v.y), f2bf(v.z), f2bf(v.w));
  }
}

__global__ __launch_bounds__(256) void k_transpose(const float* __restrict__ in,
                                                   u16* __restrict__ out, int R, int C) {
  __shared__ u16 tile[32][33];
  int c0 = blockIdx.x * 32, r0 = blockIdx.y * 32;
  int tx = threadIdx.x & 31, ty = threadIdx.x >> 5;
  for (int i = 0; i < 32; i += 8)
    tile[ty + i][tx] = f2bf(in[(size_t)(r0 + ty + i) * C + c0 + tx]);
  __syncthreads();
  for (int i = 0; i < 32; i += 8)
    out[(size_t)(c0 + ty + i) * R + r0 + tx] = tile[tx][ty + i];
}

// ---------------------------------------------------------------------------
// 256x256 QKV GEMM, K=1024. 512 thr = 8 waves (2M x 4N), per-wave 128x64 out
// via 32x32x16 MFMA (acc[4][2] f32x16 in AGPRs). BK=64. LDS = 2 tile-bufs x
// {A,B} x 2 halves x (128 x 128B) = 128 KB, 16B-granule ^(row&7) swizzle.
//
// Uniform 4-phase schedule (ALL waves identical; clusters = output quadrants):
//   P0: read aR[0,1]+bR[0] (12 ds_read_b128) | bar | MFMA C0 (acc[0..1][0]) | bar
//   P1: read aR[2,3] (8)                     | bar | MFMA C1 (acc[2..3][0]) | bar
//   P2: read bR[1] (4); STAGE A0,A1(T+2)     | bar | MFMA C2 (acc[0..1][1]) | bar
//   P3: STAGE B0,B1(T+2)                     | bar | MFMA C3 (acc[2..3][1]);
//       vmcnt(8) [T==NT-2: 0; T==NT-1: none] | bar
// Race-freedom: region last-reads: A(T)@P1, B(T)@P2; restage A@P2, B@P3 --
// each >=1 lgkm-drained barrier after the last read. Cross-wave data guard:
// per-wave vmcnt + barrier at P3-end publishes tile T+1 before its P0 reads
// (each half has 5-6 phases of HBM slack). Single counted wait per K-tile.
__global__ __launch_bounds__(512, 2) void k_gemm256(
    const u16* __restrict__ A, const u16* __restrict__ Bt,
    const float* __restrict__ bias,
    u16* __restrict__ qb, u16* __restrict__ kb, u16* __restrict__ vb) {
  const int K = 1024, NT = 16;
  __shared__ u16 lds[2][2][2][8192];  // [buf][A/B][half][128*64]
  const int b0 = blockIdx.x;
  const int bsw = (b0 & 7) * 48 + (b0 >> 3);  // XCD swizzle (384 % 8 == 0)
  const int tm = bsw / 12, tn = bsw % 12;
  const int t = threadIdx.x, w = t >> 6, lane = t & 63;
  const int wm = w >> 2, wn = w & 3, hb = wn >> 1;
  const int l31 = lane & 31, h8 = lane >> 5;
  const int sg8 = ((lane & 7) ^ ((lane >> 3) & 7)) << 3;  // staging src swizzle
  const u16* Ag = A + (size_t)tm * 256 * K;
  const u16* Bg = Bt + (size_t)tn * 256 * K;

  f32x16 acc[4][2] = {};
  bf16x8 aR[4][4], bR[2][4];

#define STG(ab, hf, Tn, BUF)                                                \
  { const u16* gb = (ab) ? Bg : Ag;                                         \
    _Pragma("unroll") for (int r = 0; r < 2; r++) {                         \
      int row = r * 64 + w * 8 + ((lane >> 3) & 7);                         \
      gload16(gb + (size_t)((hf)*128 + row) * K + (size_t)(Tn)*64 + sg8,    \
              (char*)&lds[BUF][ab][hf][0] + r * 8192 + w * 1024);           \
    } }
#define RDA(mf, BUF)                                                        \
  _Pragma("unroll") for (int ks = 0; ks < 4; ks++)                          \
    aR[mf][ks] = *(const bf16x8*)((const char*)&lds[BUF][0][wm][0] +        \
        ((mf)*32 + l31) * 128 + (((ks * 2 + h8) ^ (l31 & 7)) << 4));
#define RDB(nf, BUF)                                                        \
  _Pragma("unroll") for (int ks = 0; ks < 4; ks++)                          \
    bR[nf][ks] = *(const bf16x8*)((const char*)&lds[BUF][1][hb][0] +        \
        (((wn & 1) * 64 + (nf)*32 + l31)) * 128 +                           \
        (((ks * 2 + h8) ^ (l31 & 7)) << 4));
#define MQ(mg, nf)                                                          \
  { __builtin_amdgcn_s_setprio(1);                                         \
    _Pragma("unroll") for (int ks = 0; ks < 4; ks++) {                      \
      acc[(mg)*2][nf] = __builtin_amdgcn_mfma_f32_32x32x16_bf16(            \
          aR[(mg)*2][ks], bR[nf][ks], acc[(mg)*2][nf], 0, 0, 0);            \
      acc[(mg)*2 + 1][nf] = __builtin_amdgcn_mfma_f32_32x32x16_bf16(        \
          aR[(mg)*2 + 1][ks], bR[nf][ks], acc[(mg)*2 + 1][nf], 0, 0, 0);    \
    }                                                                       \
    __builtin_amdgcn_s_setprio(0); }
#define BAR()                                                               \
  { __builtin_amdgcn_sched_barrier(0); __builtin_amdgcn_s_barrier();        \
    __builtin_amdgcn_sched_barrier(0); }

  // prologue: stage tiles 0 and 1 (order A0,A1,B0,B1 per tile = ledger order)
  STG(0, 0, 0, 0) STG(0, 1, 0, 0) STG(1, 0, 0, 0) STG(1, 1, 0, 0)
  STG(0, 0, 1, 1) STG(0, 1, 1, 1) STG(1, 0, 1, 1) STG(1, 1, 1, 1)
  asm volatile("s_waitcnt vmcnt(8)" ::: "memory");  // tile 0 arrived
  BAR();

#define TILE(T, BUF)                                                        \
  { /* P0 */                                                                \
    RDA(0, BUF) RDA(1, BUF) RDB(0, BUF)                                     \
    BAR(); MQ(0, 0) BAR();                                                  \
    /* P1 */                                                                \
    RDA(2, BUF) RDA(3, BUF)                                                 \
    BAR(); MQ(1, 0) BAR();                                                  \
    /* P2 */                                                                \
    RDB(1, BUF)                                                             \
    if ((T) + 2 < NT) { STG(0, 0, (T) + 2, BUF) STG(0, 1, (T) + 2, BUF) }   \
    BAR(); MQ(0, 1) BAR();                                                  \
    /* P3 */                                                                \
    if ((T) + 2 < NT) { STG(1, 0, (T) + 2, BUF) STG(1, 1, (T) + 2, BUF) }   \
    BAR(); MQ(1, 1)                                                         \
    if ((T) < NT - 2) {                                                     \
      asm volatile("s_waitcnt vmcnt(8)" ::: "memory");                      \
    } else if ((T) == NT - 2) {                                             \
      asm volatile("s_waitcnt vmcnt(0)" ::: "memory");                      \
    }                                                                       \
    BAR(); }

  for (int Tp = 0; Tp < NT; Tp += 2) {
    TILE(Tp, 0)
    TILE(Tp + 1, 1)
  }

  // epilogue: C/D 32x32 layout col = l&31, row = (r&3)+8*(r>>2)+4*h8  [verified r2/r4]
  const int which = tn >> 2;  // block-uniform: 0=Q 1=K 2=V
#pragma unroll
  for (int mf = 0; mf < 4; mf++) {
    const int rb = tm * 256 + wm * 128 + mf * 32 + 4 * h8;
    const int b_ = rb >> 11, sB = rb & 2047;  // tile never crosses batch
#pragma unroll
    for (int nf = 0; nf < 2; nf++) {
      const int cl = tn * 256 + wn * 64 + nf * 32 + l31;
      const float bv = bias[cl];
      const int hd = (cl >> 6) & 15, d = cl & 63;
      const size_t bh = (size_t)(b_ * 16 + hd);
      if (which == 0) {  // Q, pre-scaled for exp2-domain softmax
        u16* dst = qb + (bh * 2048 + sB) * 64 + d;
#pragma unroll
        for (int r = 0; r < 16; r++)
          dst[(size_t)((r & 3) + 8 * (r >> 2)) * 64] = f2bf((acc[mf][nf][r] + bv) * QSCALE);
      } else if (which == 1) {
        u16* dst = kb + (bh * 2048 + sB) * 64 + d;
#pragma unroll
        for (int r = 0; r < 16; r++)
          dst[(size_t)((r & 3) + 8 * (r >> 2)) * 64] = f2bf(acc[mf][nf][r] + bv);
      } else {  // V^T [B,H,Dh,S]; s runs of 4 -> ushort4
        u16* dst = vb + (bh * 64 + d) * 2048 + sB;
#pragma unroll
        for (int rq = 0; rq < 4; rq++) {
          ushort4 pk = make_ushort4(
              f2bf(acc[mf][nf][rq * 4 + 0] + bv), f2bf(acc[mf][nf][rq * 4 + 1] + bv),
              f2bf(acc[mf][nf][rq * 4 + 2] + bv), f2bf(acc[mf][nf][rq * 4 + 3] + bv));
          *(ushort4*)&dst[rq * 8] = pk;
        }
      }
    }
  }
#undef STG
#undef RDA
#undef RDB
#undef MQ
#undef BAR
#undef TILE
}

// ---------------------------------------------------------------------------
// m97-structure GEMM (kept for the projection): C = A @ Bt^T + bias, fp32 out.
template <int MODE>
__global__ __launch_bounds__(256, 2) void k_gemm(
    const u16* __restrict__ A, const u16* __restrict__ Bt,
    const float* __restrict__ bias, float* __restrict__ outF,
    int M, int N, int K) {
  __shared__ u16 sA[128 * 32];
  __shared__ u16 sB[128 * 32];
  const int nTn = N >> 7;
  const int tm = blockIdx.x / nTn, tn = blockIdx.x % nTn;
  const int t = threadIdx.x, w = t >> 6, lane = t & 63, g = lane >> 4, c = lane & 15;
  const int wr = w >> 1, wc = w & 1;
  const int rowA0 = tm << 7, colB0 = tn << 7;
  f32x4 acc[4][4] = {};
  const int r = t >> 2, c8 = (t & 3) << 3;
  const u16* gA = A + (size_t)(rowA0 + r) * K + c8;
  const u16* gB = Bt + (size_t)(colB0 + r) * K + c8;
  char* lA = (char*)sA + w * 1024;
  char* lB = (char*)sB + w * 1024;
  for (int k0 = 0; k0 < K; k0 += 32) {
    __syncthreads();
    gload16(gA + k0, lA);
    gload16(gA + k0 + (size_t)64 * K, lA + 4096);
    gload16(gB + k0, lB);
    gload16(gB + k0 + (size_t)64 * K, lB + 4096);
    __syncthreads();
    bf16x8 af[4], bfr[4];
#pragma unroll
    for (int mi = 0; mi < 4; mi++)
      af[mi] = *(const bf16x8*)&sA[(wr * 64 + mi * 16 + c) * 32 + g * 8];
#pragma unroll
    for (int ni = 0; ni < 4; ni++)
      bfr[ni] = *(const bf16x8*)&sB[(wc * 64 + ni * 16 + c) * 32 + g * 8];
#pragma unroll
    for (int mi = 0; mi < 4; mi++)
#pragma unroll
      for (int ni = 0; ni < 4; ni++)
        acc[mi][ni] = __builtin_amdgcn_mfma_f32_16x16x32_bf16(af[mi], bfr[ni], acc[mi][ni], 0, 0, 0);
  }
#pragma unroll
  for (int mi = 0; mi < 4; mi++) {
    int row0 = rowA0 + wr * 64 + mi * 16 + g * 4;
#pragma unroll
    for (int ni = 0; ni < 4; ni++) {
      int col = colB0 + wc * 64 + ni * 16 + c;
      float bv = bias[col];
#pragma unroll
      for (int i = 0; i < 4; i++)
        outF[(size_t)(row0 + i) * N + col] = acc[mi][ni][i] + bv;
    }
  }
}

// ---------------------------------------------------------------------------
// Flash attention, 32x32x16 MFMA (unchanged from round 2).
__global__ __launch_bounds__(256, 4) void k_attn(const u16* __restrict__ qb,
                                                 const u16* __restrict__ kb,
                                                 const u16* __restrict__ vb,
                                                 u16* __restrict__ ab) {
  __shared__ u16 sK[2][64 * 64];
  __shared__ u16 sV[2][64 * 64];
  const int bid = blockIdx.x;
  const int qt = 15 - (bid >> 6), bh = bid & 63;
  const int b_ = bh >> 4, hh = bh & 15;
  const int t = threadIdx.x, w = t >> 6, lane = t & 63;
  const int l31 = lane & 31, h = lane >> 5;
  const int q0 = qt << 7, myq = q0 + w * 32;
  const u16* Kg = kb + (size_t)bh * 2048 * 64;
  const u16* Vg = vb + (size_t)bh * 64 * 2048;
  const int rr = t >> 3, p = t & 7;

  const u16* Qrow = qb + ((size_t)bh * 2048 + myq + l31) * 64;
  bf16x8 qf[4];
#pragma unroll
  for (int ks = 0; ks < 4; ks++) qf[ks] = *(const bf16x8*)&Qrow[ks * 16 + h * 8];

#define STAGE(buf, kv0_)                                                      \
  {                                                                           \
    _Pragma("unroll") for (int i = 0; i < 2; i++) {                           \
      int row = i * 32 + rr;                                                  \
      gload16(Kg + ((size_t)(kv0_) + row) * 64 + ((p ^ (row & 7)) << 3),      \
              (char*)sK[buf] + i * 4096 + w * 1024);                          \
      gload16(Vg + (size_t)row * 2048 + (kv0_) + ((p ^ (row & 7)) << 3),      \
              (char*)sV[buf] + i * 4096 + w * 1024);                          \
    }                                                                         \
  }

  f32x16 ot[2] = {};
  float mrun = -__builtin_inff(), lrun = 0.f;
  const int nt = qt * 2 + 2;

  STAGE(0, 0);
  for (int tt = 0; tt < nt; ++tt) {
    const int kv0 = tt << 6;
    __syncthreads();
    if (tt + 1 < nt) STAGE((tt + 1) & 1, kv0 + 64);
    if (kv0 > myq + 31) continue;
    const char* bK = (const char*)sK[tt & 1];
    const char* bV = (const char*)sV[tt & 1];

    f32x16 st[2] = {};
    __builtin_amdgcn_s_setprio(1);
#pragma unroll
    for (int ks = 0; ks < 4; ks++)
#pragma unroll
      for (int kvt = 0; kvt < 2; kvt++) {
        int row = kvt * 32 + l31;
        bf16x8 kf = *(const bf16x8*)(bK + row * 128 + ((ks * 32 + h * 16) ^ ((row & 7) << 4)));
        st[kvt] = __builtin_amdgcn_mfma_f32_32x32x16_bf16(kf, qf[ks], st[kvt], 0, 0, 0);
      }
    __builtin_amdgcn_s_setprio(0);

    if (kv0 + 63 > myq) {
      const int qm = myq + l31 - kv0 - 4 * h;
#pragma unroll
      for (int kvt = 0; kvt < 2; kvt++)
#pragma unroll
        for (int r = 0; r < 16; r++) {
          const int kvo = kvt * 32 + (r & 3) + 8 * (r >> 2);
          st[kvt][r] = (kvo <= qm) ? st[kvt][r] : -__builtin_inff();
        }
    }

    float mt = -__builtin_inff();
#pragma unroll
    for (int r = 0; r < 16; r++) mt = fmaxf(mt, fmaxf(st[0][r], st[1][r]));
    mt = fmaxf(mt, __shfl_xor(mt, 32, 64));
    float mnew = mrun;
    if (!__all(mt <= mrun + 8.f)) {
      mnew = fmaxf(mrun, mt);
      const float corr = __builtin_amdgcn_exp2f(mrun - mnew);
      lrun *= corr;
#pragma unroll
      for (int df = 0; df < 2; df++) ot[df] *= corr;
      mrun = mnew;
    }
#pragma unroll
    for (int kvt = 0; kvt < 2; kvt++)
#pragma unroll
      for (int r = 0; r < 16; r++) st[kvt][r] = __builtin_amdgcn_exp2f(st[kvt][r] - mnew);
    f32x16 ssum = st[0] + st[1];
    f32x8 t8 = __builtin_shufflevector(ssum, ssum, 0, 1, 2, 3, 4, 5, 6, 7) +
               __builtin_shufflevector(ssum, ssum, 8, 9, 10, 11, 12, 13, 14, 15);
    f32x4 t4 = __builtin_shufflevector(t8, t8, 0, 1, 2, 3) +
               __builtin_shufflevector(t8, t8, 4, 5, 6, 7);
    float lt = (t4[0] + t4[1]) + (t4[2] + t4[3]);
    lt += __shfl_xor(lt, 32, 64);
    lrun += lt;

    u32 pk[2][8];
#pragma unroll
    for (int kvt = 0; kvt < 2; kvt++)
#pragma unroll
      for (int j = 0; j < 8; j++)
        pk[kvt][j] = cvt_pk_bf16(st[kvt][2 * j], st[kvt][2 * j + 1]);
    __builtin_amdgcn_s_setprio(1);
#pragma unroll
    for (int s = 0; s < 4; s++) {
      const int kvf = s >> 1, jb = (s & 1) * 4;
      const u32 XloW0 = pk[kvf][jb + 0], XloW1 = pk[kvf][jb + 1];
      const u32 XhiW0 = pk[kvf][jb + 2], XhiW1 = pk[kvf][jb + 3];
      const u32 cHi0 = (u32)__shfl_xor((int)XhiW0, 32, 64);
      const u32 cHi1 = (u32)__shfl_xor((int)XhiW1, 32, 64);
      const u32 cLo0 = (u32)__shfl_xor((int)XloW0, 32, 64);
      const u32 cLo1 = (u32)__shfl_xor((int)XloW1, 32, 64);
      u32x4 pw;
      pw[0] = h ? cHi0 : XloW0;
      pw[1] = h ? cHi1 : XloW1;
      pw[2] = h ? XhiW0 : cLo0;
      pw[3] = h ? XhiW1 : cLo1;
      const bf16x8 pf = __builtin_bit_cast(bf16x8, pw);
#pragma unroll
      for (int df = 0; df < 2; df++) {
        const int row = df * 32 + l31;
        bf16x8 vf = *(const bf16x8*)(bV + row * 128 + ((s * 32 + h * 16) ^ ((row & 7) << 4)));
        ot[df] = __builtin_amdgcn_mfma_f32_32x32x16_bf16(vf, pf, ot[df], 0, 0, 0);
      }
    }
    __builtin_amdgcn_s_setprio(0);
  }

  const float inv = 1.f / lrun;
  u16* Arow = ab + ((size_t)b_ * 2048 + myq + l31) * 1024 + hh * 64;
#pragma unroll
  for (int df = 0; df < 2; df++)
#pragma unroll
    for (int qd = 0; qd < 4; qd++) {
      const int d0 = df * 32 + qd * 8 + h * 4;
      ushort4 pkv = make_ushort4(f2bf(ot[df][qd * 4 + 0] * inv), f2bf(ot[df][qd * 4 + 1] * inv),
                                 f2bf(ot[df][qd * 4 + 2] * inv), f2bf(ot[df][qd * 4 + 3] * inv));
      *(ushort4*)&Arow[d0] = pkv;
    }
#undef STAGE
}

// ---------------------------------------------------------------------------
extern "C" void kernel_launch(void* const* d_in, const int* in_sizes, int n_in,
                              void* d_out, int out_size, void* d_ws, size_t ws_size,
                              hipStream_t stream) {
  const float* x = (const float*)d_in[0];
  const float* w_qkv = (const float*)d_in[1];
  const float* b_qkv = (const float*)d_in[2];
  const float* w_proj = (const float*)d_in[3];
  const float* b_proj = (const float*)d_in[4];

  u16* xb = (u16*)d_ws;                       // 8192*1024
  u16* wqkvT = xb + (size_t)8192 * 1024;      // 3072*1024
  u16* wprojT = wqkvT + (size_t)3072 * 1024;  // 1024*1024
  u16* qb = wprojT + (size_t)1024 * 1024;     // [B,H,S,Dh] (pre-scaled)
  u16* kb = qb + (size_t)8192 * 1024;
  u16* vb = kb + (size_t)8192 * 1024;         // [B,H,Dh,S]
  u16* ab = xb;                               // reuse x_bf16

  k_cvt<<<8192, 256, 0, stream>>>((const float4*)x, (ushort4*)xb, 8192 * 1024 / 4);
  k_transpose<<<dim3(3072 / 32, 1024 / 32), 256, 0, stream>>>(w_qkv, wqkvT, 1024, 3072);
  k_transpose<<<dim3(1024 / 32, 1024 / 32), 256, 0, stream>>>(w_proj, wprojT, 1024, 1024);
  k_gemm256<<<384, 512, 0, stream>>>(xb, wqkvT, b_qkv, qb, kb, vb);
  k_attn<<<1024, 256, 0, stream>>>(qb, kb, vb, ab);
  k_gemm<1><<<(8192 / 128) * (1024 / 128), 256, 0, stream>>>(
      ab, wprojT, b_proj, (float*)d_out, 8192, 1024, 1024);
}